// Round 3
// baseline (152.852 us; speedup 1.0000x reference)
//
#include <hip/hip_runtime.h>
#include <hip/hip_bf16.h>
#include <math.h>

// B=2, T=2048, D=1024, H=16, hd=64, ALPHA=1 (decay = -(i-j))
// Pipeline: fused cast f32->bf16
//  -> QKV as ONE 8-phase NT GEMM over stacked W [3072x1024] (tile 256x192,
//     grid 16x16 = 256 blocks = 1/CU perfectly balanced; per-phase barrier
//     pairs + front-loaded stage issue + aged vmcnt + setprio = T3+T4+T5)
//  -> windowed flash attn (j-tiles {qb-1,qb}; decay kills distance>64)
//  -> out NT GEMM (128x128 dbuf).
// NOTE: ~86us of dur_us is two 268MB harness poison-fills (43us each, seen in
// rocprof top-5); controllable kernel budget is ~64us.

typedef __bf16 bf16_t;
typedef bf16_t bf16x8 __attribute__((ext_vector_type(8)));
typedef bf16_t bf16x4 __attribute__((ext_vector_type(4)));
typedef float  floatx4 __attribute__((ext_vector_type(4)));

#define LOG2E 1.44269504088896f

#if __has_builtin(__builtin_amdgcn_exp2f)
#define EXP2(x) __builtin_amdgcn_exp2f(x)
#else
#define EXP2(x) exp2f(x)
#endif

__device__ __forceinline__ void async16(const bf16_t* g, bf16_t* l) {
  __builtin_amdgcn_global_load_lds(
      (const __attribute__((address_space(1))) unsigned int*)g,
      (__attribute__((address_space(3))) unsigned int*)l, 16, 0, 0);
}

// pack two f32 into bf16x2 by truncation (1 v_perm_b32); P>=0 -> rel err <= 2^-8
__device__ __forceinline__ unsigned pack_bf16_trunc(float lo, float hi) {
  return __builtin_amdgcn_perm(__builtin_bit_cast(unsigned, hi),
                               __builtin_bit_cast(unsigned, lo), 0x07060302u);
}

// ---------------- fused cast kernel ----------------
__global__ void castall(const float* __restrict__ x,
                        const float* __restrict__ wq, const float* __restrict__ wk,
                        const float* __restrict__ wv, const float* __restrict__ wo,
                        bf16_t* __restrict__ xb, bf16_t* __restrict__ wdst) {
  int i = blockIdx.x * blockDim.x + threadIdx.x;  // 0 .. 2097151
  const float* src;
  bf16_t* dst;
  if (i < 1048576) {
    src = x + (size_t)i * 4;
    dst = xb + (size_t)i * 4;
  } else {
    int i2 = i - 1048576;
    int wsel = i2 >> 18;
    int off = i2 & 262143;
    const float* wsrc = (wsel == 0) ? wq : (wsel == 1) ? wk : (wsel == 2) ? wv : wo;
    src = wsrc + (size_t)off * 4;
    dst = wdst + (size_t)i2 * 4;
  }
  const float4 f = *(const float4*)src;
  bf16x4 o;
  o[0] = (bf16_t)f.x; o[1] = (bf16_t)f.y; o[2] = (bf16_t)f.z; o[3] = (bf16_t)f.w;
  *(bf16x4*)dst = o;
}

// ---------------- QKV 8-phase NT GEMM: C[4096x3072] = A[4096x1024] . Wst^T ----------------
// Tile 256x192, BK=64, 8 waves (2M x 4N -> 128x48/wave), 4 phases/K-tile.
// Per phase: 7 ds_read_b128 (4 A-frag + 3 B-frag) + stage-part issue ->
// barrier -> setprio(1) 12 MFMA setprio(0) -> barrier.
// Stage issue front-loaded (phases 0-2) so boundary vmcnt(0) waits only on
// loads aged >= 2 phases (~free). LDS 112 KB, 1 block/CU.
#define BK 64

__global__ __launch_bounds__(512, 1)
void gemm_qkv8(const bf16_t* __restrict__ A, const bf16_t* __restrict__ Wst,
               const float* __restrict__ b0, const float* __restrict__ b1,
               const float* __restrict__ b2,
               bf16_t* __restrict__ O0, bf16_t* __restrict__ O1,
               bf16_t* __restrict__ O2)
{
  __shared__ __align__(16) bf16_t As[2][256 * BK];   // 64 KB
  __shared__ __align__(16) bf16_t Bs[2][192 * BK];   // 48 KB
  const int t = threadIdx.x, w = t >> 6, lane = t & 63;
  const int l15 = lane & 15, q4 = lane >> 4;
  const int orig = blockIdx.x;
  const int wgid = (orig & 7) * 32 + (orig >> 3);    // XCD-bijective swizzle
  const int m0 = (wgid >> 4) * 256, n0 = (wgid & 15) * 192;
  const int wm = (w >> 2) * 128, wn = (w & 3) * 48;  // 2M x 4N wave grid

  floatx4 acc[8][3];
#pragma unroll
  for (int i = 0; i < 8; ++i)
#pragma unroll
    for (int j = 0; j < 3; ++j) acc[i][j] = (floatx4){0.f, 0.f, 0.f, 0.f};

  // staging: chunk = 16B seg; row = chunk>>3; phys slot chunk&7 holds global
  // seg (chunk&7)^(row&7) (XOR swizzle, row stride 128 B)
  auto stageA = [&](int buf, int k0, int c) {
    int ch = t + c * 512; int row = ch >> 3; int g = (ch & 7) ^ (row & 7);
    async16(A + (size_t)(m0 + row) * 1024 + k0 + g * 8, &As[buf][ch * 8]);
  };
  auto stageB = [&](int buf, int k0, int c) {
    int ch = t + c * 512; int row = ch >> 3; int g = (ch & 7) ^ (row & 7);
    async16(Wst + (size_t)(n0 + row) * 1024 + k0 + g * 8, &Bs[buf][ch * 8]);
  };

  // prologue: stage K-tile 0 fully, drain, publish
#pragma unroll
  for (int c = 0; c < 4; ++c) stageA(0, 0, c);
#pragma unroll
  for (int c = 0; c < 3; ++c) stageB(0, 0, c);
  asm volatile("s_waitcnt vmcnt(0)" ::: "memory");
  __builtin_amdgcn_s_barrier();

  for (int kt = 0; kt < 16; ++kt) {
    const int cur = kt & 1;
    const int k1 = (kt + 1) * BK;
    const bool pf = (kt < 15);

#pragma unroll
    for (int p = 0; p < 4; ++p) {
      const int pm = p >> 1, kk = p & 1;   // quadrant: m-half x k-half
      bf16x8 af[4], bfr[3];
#pragma unroll
      for (int i = 0; i < 4; ++i) {
        int ra = wm + (pm * 4 + i) * 16 + l15;
        int sg = (kk * 4 + q4) ^ (ra & 7);
        af[i] = *(const bf16x8*)&As[cur][ra * BK + sg * 8];
      }
#pragma unroll
      for (int j = 0; j < 3; ++j) {
        int rb = wn + j * 16 + l15;
        int sg = (kk * 4 + q4) ^ (rb & 7);
        bfr[j] = *(const bf16x8*)&Bs[cur][rb * BK + sg * 8];
      }
      if (pf) {   // front-loaded prefetch issue: 3,3,1,0 loads/thread
        if (p == 0)      { stageA(cur ^ 1, k1, 0); stageA(cur ^ 1, k1, 1); stageB(cur ^ 1, k1, 0); }
        else if (p == 1) { stageA(cur ^ 1, k1, 2); stageA(cur ^ 1, k1, 3); stageB(cur ^ 1, k1, 1); }
        else if (p == 2) { stageB(cur ^ 1, k1, 2); }
      }
      __builtin_amdgcn_s_barrier();
      __builtin_amdgcn_s_setprio(1);
#pragma unroll
      for (int i = 0; i < 4; ++i)
#pragma unroll
        for (int j = 0; j < 3; ++j)
          acc[pm * 4 + i][j] = __builtin_amdgcn_mfma_f32_16x16x32_bf16(
              af[i], bfr[j], acc[pm * 4 + i][j], 0, 0, 0);
      __builtin_amdgcn_s_setprio(0);
      if (p < 3) __builtin_amdgcn_s_barrier();
    }
    // K-tile boundary: prefetch (aged >= 2 phases) must have landed for all
    asm volatile("s_waitcnt vmcnt(0)" ::: "memory");
    __builtin_amdgcn_s_barrier();
  }

  // epilogue; C/D layout: col = lane&15, row = (lane>>4)*4 + reg
#pragma unroll
  for (int i = 0; i < 8; ++i) {
    const int row = m0 + wm + i * 16 + q4 * 4;
#pragma unroll
    for (int j = 0; j < 3; ++j) {
      const int col = n0 + wn + j * 16 + l15;
      const int cmat = col >> 10, lcol = col & 1023;   // frag never straddles
      const float* bp = (cmat == 0) ? b0 : (cmat == 1) ? b1 : b2;
      const float bv = bp[lcol];
      if (cmat == 2) {
        // V transposed: Vt[b][d][t]; lane holds 4 consecutive t -> 8B store
        int bb = row >> 11, tt = row & 2047;
        bf16x4 pk;
#pragma unroll
        for (int r = 0; r < 4; ++r) pk[r] = (bf16_t)(acc[i][j][r] + bv);
        *(bf16x4*)(O2 + (size_t)(bb * 1024 + lcol) * 2048 + tt) = pk;
      } else {
        bf16_t* Om = cmat ? O1 : O0;
#pragma unroll
        for (int r = 0; r < 4; ++r)
          Om[(size_t)(row + r) * 1024 + lcol] = (bf16_t)(acc[i][j][r] + bv);
      }
    }
  }
}

// ---------------- out NT GEMM: 128x128 tile, dbuf, 1 block/CU (f32 out) ----------------
__global__ __launch_bounds__(512, 2)
void gemm_out(const bf16_t* __restrict__ A, const bf16_t* __restrict__ Wm,
              const float* __restrict__ bias, float* __restrict__ OF)
{
  __shared__ __align__(16) bf16_t As[2][128 * BK];   // 32 KB
  __shared__ __align__(16) bf16_t Bs[2][128 * BK];   // 32 KB
  const int t = threadIdx.x, w = t >> 6, lane = t & 63;
  const int l15 = lane & 15, q4 = lane >> 4;
  const int orig = blockIdx.x;
  const int wgid = (orig & 7) * 32 + (orig >> 3);    // XCD-bijective swizzle
  const int mb = wgid >> 3, nbk = wgid & 7;          // 32 m x 8 n
  const int m0 = mb * 128, n0 = nbk * 128;
  const int wm = (w >> 2) * 64, wn = (w & 3) * 32;   // 2x4 wave grid over 128x128

  floatx4 acc[4][2];
#pragma unroll
  for (int mi = 0; mi < 4; ++mi)
#pragma unroll
    for (int ni = 0; ni < 2; ++ni) acc[mi][ni] = (floatx4){0.f, 0.f, 0.f, 0.f};

  auto stage = [&](int buf, int k0) {
#pragma unroll
    for (int c = 0; c < 2; ++c) {
      int chunk = t + c * 512;                 // 0..1023
      int row = chunk >> 3;
      int g = (chunk & 7) ^ (row & 7);
      async16(A  + (size_t)(m0 + row) * 1024 + k0 + g * 8, &As[buf][chunk * 8]);
      async16(Wm + (size_t)(n0 + row) * 1024 + k0 + g * 8, &Bs[buf][chunk * 8]);
    }
  };

  stage(0, 0);
  __syncthreads();
  for (int it = 0; it < 16; ++it) {
    const int cur = it & 1;
    if (it + 1 < 16) stage(cur ^ 1, (it + 1) * BK);

#pragma unroll
    for (int kk = 0; kk < 2; ++kk) {
      bf16x8 af[4], bfr[2];
#pragma unroll
      for (int i = 0; i < 4; ++i) {
        int ra = wm + i * 16 + l15;
        int pa = (kk * 4 + q4) ^ (ra & 7);
        af[i] = *(const bf16x8*)&As[cur][ra * BK + pa * 8];
      }
#pragma unroll
      for (int i = 0; i < 2; ++i) {
        int rb = wn + i * 16 + l15;
        int pb = (kk * 4 + q4) ^ (rb & 7);
        bfr[i] = *(const bf16x8*)&Bs[cur][rb * BK + pb * 8];
      }
#pragma unroll
      for (int mi = 0; mi < 4; ++mi)
#pragma unroll
        for (int ni = 0; ni < 2; ++ni)
          acc[mi][ni] = __builtin_amdgcn_mfma_f32_16x16x32_bf16(
              af[mi], bfr[ni], acc[mi][ni], 0, 0, 0);
    }
    __syncthreads();
  }

#pragma unroll
  for (int mi = 0; mi < 4; ++mi)
#pragma unroll
    for (int ni = 0; ni < 2; ++ni) {
      const int col = n0 + wn + ni * 16 + l15;
      const float bv = bias[col];
#pragma unroll
      for (int r = 0; r < 4; ++r) {
        int row = m0 + wm + mi * 16 + q4 * 4 + r;
        OF[(size_t)row * 1024 + col] = acc[mi][ni][r] + bv;
      }
    }
}

// ---------------- windowed flash attention: j-tiles {qb-1, qb} only ----------------
// decay e^{-(i-j)} makes keys at distance >64 weigh < e^{-58}: below f32 ulp.
__global__ __launch_bounds__(256, 3)
void attn_kernel(const bf16_t* __restrict__ Qb, const bf16_t* __restrict__ Kb,
                 const bf16_t* __restrict__ Vt, bf16_t* __restrict__ AO)
{
  __shared__ __align__(16) bf16_t Ks[2][64 * 64];
  __shared__ __align__(16) bf16_t Vs[2][64 * 64];
  __shared__ __align__(16) bf16_t Ps[4][16][72];

  const int t = threadIdx.x, w = t >> 6, lane = t & 63;
  const int l15 = lane & 15, q4 = lane >> 4;
  const int bh = blockIdx.x & 31, qb = blockIdx.x >> 5;
  const int b = bh >> 4, h = bh & 15;
  const int i0 = qb * 64;
  const int jstart = (qb > 0) ? (qb - 1) : 0;
  const int nIter = qb - jstart + 1;      // 1 (qb==0) or 2

  const float C1 = 0.125f * LOG2E;        // (1/sqrt(64)) * log2e
  const float CL = LOG2E;
  const float Er[4] = {1.0f, 2.71828182846f, 7.38905609893f, 20.0855369232f};

  const bf16_t* qp = Qb + ((size_t)(b * 2048 + i0 + w * 16 + l15)) * 1024 + h * 64 + q4 * 8;
  const bf16x8 qf0 = *(const bf16x8*)qp;
  const bf16x8 qf1 = *(const bf16x8*)(qp + 32);

  floatx4 o_acc[4], lsum;
  lsum = (floatx4){0.f, 0.f, 0.f, 0.f};
#pragma unroll
  for (int dt = 0; dt < 4; ++dt) o_acc[dt] = (floatx4){0.f, 0.f, 0.f, 0.f};
  bf16x8 ones;
#pragma unroll
  for (int e = 0; e < 8; ++e) ones[e] = (bf16_t)1.0f;

  float dm[4];
#pragma unroll
  for (int mt = 0; mt < 4; ++mt)
    dm[mt] = (float)(jstart * 64 + mt * 16 + q4 * 4 - w * 16 - l15 - i0) * CL;
  const int relMask = w * 16 + l15;

  const int chA = w * 128 + lane, chB = chA + 64;
  const int rA = chA >> 3, rB = chB >> 3;
  const int sA = (chA & 7) ^ (rA & 7), sB = (chB & 7) ^ (rB & 7);
  const bf16_t* kpA = Kb + ((size_t)(b * 2048 + jstart * 64 + rA)) * 1024 + h * 64 + sA * 8;
  const bf16_t* kpB = Kb + ((size_t)(b * 2048 + jstart * 64 + rB)) * 1024 + h * 64 + sB * 8;
  const bf16_t* vpA = Vt + ((size_t)(b * 1024 + h * 64 + rA)) * 2048 + jstart * 64 + sA * 8;
  const bf16_t* vpB = Vt + ((size_t)(b * 1024 + h * 64 + rB)) * 2048 + jstart * 64 + sB * 8;

  auto stage = [&](int buf) {
    async16(kpA, &Ks[buf][chA * 8]);
    async16(kpB, &Ks[buf][chB * 8]);
    async16(vpA, &Vs[buf][chA * 8]);
    async16(vpB, &Vs[buf][chB * 8]);
    kpA += 65536; kpB += 65536;
    vpA += 64;    vpB += 64;
  };

  stage(0);
  for (int it = 0; it < nIter; ++it) {
    __syncthreads();
    if (it + 1 < nIter) stage(1);
    const int cur = it;

    const bool diag = (it == nIter - 1);
#pragma unroll
    for (int mt = 0; mt < 4; ++mt) {
      int row = mt * 16 + l15;
      int s0 = q4 ^ (row & 7);
      int s1 = (4 + q4) ^ (row & 7);
      bf16x8 kf0 = *(const bf16x8*)&Ks[cur][row * 64 + s0 * 8];
      bf16x8 kf1 = *(const bf16x8*)&Ks[cur][row * 64 + s1 * 8];
      floatx4 s4 = __builtin_amdgcn_mfma_f32_16x16x32_bf16(kf0, qf0,
                       (floatx4){0.f, 0.f, 0.f, 0.f}, 0, 0, 0);
      s4 = __builtin_amdgcn_mfma_f32_16x16x32_bf16(kf1, qf1, s4, 0, 0, 0);

      float p[4];
#pragma unroll
      for (int r = 0; r < 4; ++r) {
        float v = EXP2(fmaf(s4[r], C1, dm[mt])) * Er[r];
        if (diag && (mt * 16 + q4 * 4 + r) > relMask) v = 0.f;
        p[r] = v;
      }
      uint2 pk2;
      pk2.x = pack_bf16_trunc(p[0], p[1]);
      pk2.y = pack_bf16_trunc(p[2], p[3]);
      *(uint2*)&Ps[w][l15][mt * 16 + q4 * 4] = pk2;
      dm[mt] += 64.0f * CL;
    }

    __builtin_amdgcn_s_waitcnt(0xC07F);  // lgkmcnt(0): own-wave P writes visible

    bf16x8 pf0 = *(const bf16x8*)&Ps[w][l15][q4 * 8];
    bf16x8 pf1 = *(const bf16x8*)&Ps[w][l15][32 + q4 * 8];
    lsum = __builtin_amdgcn_mfma_f32_16x16x32_bf16(pf0, ones, lsum, 0, 0, 0);
    lsum = __builtin_amdgcn_mfma_f32_16x16x32_bf16(pf1, ones, lsum, 0, 0, 0);
#pragma unroll
    for (int dt = 0; dt < 4; ++dt) {
      int row = dt * 16 + l15;
      int s0 = q4 ^ (row & 7);
      int s1 = (4 + q4) ^ (row & 7);
      bf16x8 vf0 = *(const bf16x8*)&Vs[cur][row * 64 + s0 * 8];
      bf16x8 vf1 = *(const bf16x8*)&Vs[cur][row * 64 + s1 * 8];
      o_acc[dt] = __builtin_amdgcn_mfma_f32_16x16x32_bf16(pf0, vf0, o_acc[dt], 0, 0, 0);
      o_acc[dt] = __builtin_amdgcn_mfma_f32_16x16x32_bf16(pf1, vf1, o_acc[dt], 0, 0, 0);
    }
  }

  floatx4 inv;
#pragma unroll
  for (int r = 0; r < 4; ++r) inv[r] = 1.0f / lsum[r];
#pragma unroll
  for (int dt = 0; dt < 4; ++dt)
#pragma unroll
    for (int r = 0; r < 4; ++r) {
      int i = i0 + w * 16 + q4 * 4 + r;
      AO[((size_t)(b * 2048 + i)) * 1024 + h * 64 + dt * 16 + l15] =
          (bf16_t)(o_acc[dt][r] * inv[r]);
    }
}

// ---------------- launch ----------------
extern "C" void kernel_launch(void* const* d_in, const int* in_sizes, int n_in,
                              void* d_out, int out_size, void* d_ws, size_t ws_size,
                              hipStream_t stream) {
  const float* x  = (const float*)d_in[0];
  const float* Wq = (const float*)d_in[1];
  const float* bq = (const float*)d_in[2];
  const float* Wk = (const float*)d_in[3];
  const float* bk = (const float*)d_in[4];
  const float* Wv = (const float*)d_in[5];
  const float* bv = (const float*)d_in[6];
  const float* Wo = (const float*)d_in[7];
  const float* bo = (const float*)d_in[8];

  char* ws = (char*)d_ws;                      // needs >= 48 MB
  bf16_t* xb  = (bf16_t*)(ws);                 //  8 MB
  bf16_t* wqb = (bf16_t*)(ws + (8u  << 20));   //  2 MB (wq,wk,wv,wo contiguous)
  bf16_t* wob = (bf16_t*)(ws + (14u << 20));
  bf16_t* Qb  = (bf16_t*)(ws + (16u << 20));   //  8 MB  [b,t,h,d]
  bf16_t* Kb  = (bf16_t*)(ws + (24u << 20));   //  8 MB  [b,t,h,d]
  bf16_t* Vtb = (bf16_t*)(ws + (32u << 20));   //  8 MB  [b,h*d,t]
  bf16_t* AOb = (bf16_t*)(ws + (40u << 20));   //  8 MB  [b,t,h,d]

  castall<<<8192, 256, 0, stream>>>(x, Wq, Wk, Wv, Wo, xb, wqb);

  // QKV: one 8-phase NT GEMM over stacked W [3072x1024]; 256 blocks = 1/CU
  gemm_qkv8<<<256, 512, 0, stream>>>(
      xb, wqb, bq, bk, bv, Qb, Kb, Vtb);

  attn_kernel<<<1024, 256, 0, stream>>>(Qb, Kb, Vtb, AOb);

  // out: 256 blocks (32 m x 8 n) x 512 threads = 1 block/CU, one round
  gemm_out<<<256, 512, 0, stream>>>(AOb, wob, bo, (float*)d_out);
}

// Round 4
// 148.012 us; speedup vs baseline: 1.0327x; 1.0327x over previous
//
#include <hip/hip_runtime.h>
#include <hip/hip_bf16.h>
#include <math.h>

// B=2, T=2048, D=1024, H=16, hd=64, ALPHA=1 (decay = -(i-j))
// Pipeline: fused cast f32->bf16
//  -> QKV NT GEMM over stacked W [3072x1024]: 128x128 tiles, 256 thr,
//     single-buffered 32 KB LDS, __launch_bounds__(256,4) -> 4 blocks/CU
//     (16 waves/CU): cross-block wave overlap hides the per-K-tile vmcnt
//     drain (occupancy, not software pipelining, is the latency lever here).
//  -> windowed flash attn (j-tiles {qb-1,qb}; decay kills distance>64)
//  -> out NT GEMM (128x128 dbuf, 2 blocks/CU).
// NOTE: ~86us of dur_us is two 268MB harness poison-fills (43us each);
// controllable kernel budget is ~65us, of which qkv measured 45us (r3).

typedef __bf16 bf16_t;
typedef bf16_t bf16x8 __attribute__((ext_vector_type(8)));
typedef bf16_t bf16x4 __attribute__((ext_vector_type(4)));
typedef float  floatx4 __attribute__((ext_vector_type(4)));

#define LOG2E 1.44269504088896f

#if __has_builtin(__builtin_amdgcn_exp2f)
#define EXP2(x) __builtin_amdgcn_exp2f(x)
#else
#define EXP2(x) exp2f(x)
#endif

__device__ __forceinline__ void async16(const bf16_t* g, bf16_t* l) {
  __builtin_amdgcn_global_load_lds(
      (const __attribute__((address_space(1))) unsigned int*)g,
      (__attribute__((address_space(3))) unsigned int*)l, 16, 0, 0);
}

// pack two f32 into bf16x2 by truncation (1 v_perm_b32); P>=0 -> rel err <= 2^-8
__device__ __forceinline__ unsigned pack_bf16_trunc(float lo, float hi) {
  return __builtin_amdgcn_perm(__builtin_bit_cast(unsigned, hi),
                               __builtin_bit_cast(unsigned, lo), 0x07060302u);
}

// ---------------- fused cast kernel ----------------
__global__ void castall(const float* __restrict__ x,
                        const float* __restrict__ wq, const float* __restrict__ wk,
                        const float* __restrict__ wv, const float* __restrict__ wo,
                        bf16_t* __restrict__ xb, bf16_t* __restrict__ wdst) {
  int i = blockIdx.x * blockDim.x + threadIdx.x;  // 0 .. 2097151
  const float* src;
  bf16_t* dst;
  if (i < 1048576) {
    src = x + (size_t)i * 4;
    dst = xb + (size_t)i * 4;
  } else {
    int i2 = i - 1048576;
    int wsel = i2 >> 18;
    int off = i2 & 262143;
    const float* wsrc = (wsel == 0) ? wq : (wsel == 1) ? wk : (wsel == 2) ? wv : wo;
    src = wsrc + (size_t)off * 4;
    dst = wdst + (size_t)i2 * 4;
  }
  const float4 f = *(const float4*)src;
  bf16x4 o;
  o[0] = (bf16_t)f.x; o[1] = (bf16_t)f.y; o[2] = (bf16_t)f.z; o[3] = (bf16_t)f.w;
  *(bf16x4*)dst = o;
}

// ---------------- QKV NT GEMM: C[4096x3072] = A[4096x1024].Wst^T ----------------
// 128x128 tile, BK=64, 256 thr (4 waves, 2x2 over 64x64), single-buffer LDS,
// 4 blocks/CU, grid 768 (32m x 24n) fully co-resident.
#define BK 64

__global__ __launch_bounds__(256, 4)
void gemm_qkv(const bf16_t* __restrict__ A, const bf16_t* __restrict__ Wst,
              const float* __restrict__ b0, const float* __restrict__ b1,
              const float* __restrict__ b2,
              bf16_t* __restrict__ O0, bf16_t* __restrict__ O1,
              bf16_t* __restrict__ O2)
{
  __shared__ __align__(16) bf16_t As[128 * BK];   // 16 KB
  __shared__ __align__(16) bf16_t Bs[128 * BK];   // 16 KB
  const int t = threadIdx.x, w = t >> 6, lane = t & 63;
  const int l15 = lane & 15, q4 = lane >> 4;
  // XCD-bijective swizzle (768 = 8 * 96): each XCD covers 4 full A-panels
  // (all 24 n-blocks for each) -> A-panel + W stay L2/L3 resident.
  const int orig = blockIdx.x;
  const int wgid = (orig & 7) * 96 + (orig >> 3);
  const int mb = wgid / 24, nb = wgid % 24;       // mb 0..31, nb 0..23
  const int m0 = mb * 128, n0 = nb * 128;
  const int wm = (w >> 1) * 64, wn = (w & 1) * 64;

  floatx4 acc[4][4];
#pragma unroll
  for (int mi = 0; mi < 4; ++mi)
#pragma unroll
    for (int ni = 0; ni < 4; ++ni) acc[mi][ni] = (floatx4){0.f, 0.f, 0.f, 0.f};

  // staging: 1024 chunks (16 B) per matrix; phys slot chunk&7 holds global
  // seg (chunk&7)^(row&7) (XOR swizzle: row stride 128 B spans all banks)
  for (int k0 = 0; k0 < 1024; k0 += BK) {
#pragma unroll
    for (int c = 0; c < 4; ++c) {
      int chunk = t + c * 256;              // 0..1023
      int row = chunk >> 3;
      int g = (chunk & 7) ^ (row & 7);
      async16(A   + (size_t)(m0 + row) * 1024 + k0 + g * 8, &As[chunk * 8]);
      async16(Wst + (size_t)(n0 + row) * 1024 + k0 + g * 8, &Bs[chunk * 8]);
    }
    __syncthreads();

#pragma unroll
    for (int kk = 0; kk < 2; ++kk) {
      bf16x8 af[4], bfr[4];
#pragma unroll
      for (int i = 0; i < 4; ++i) {
        int ra = wm + i * 16 + l15;
        int rb = wn + i * 16 + l15;
        int pa = (kk * 4 + q4) ^ (ra & 7);
        int pb = (kk * 4 + q4) ^ (rb & 7);
        af[i]  = *(const bf16x8*)&As[ra * BK + pa * 8];
        bfr[i] = *(const bf16x8*)&Bs[rb * BK + pb * 8];
      }
#pragma unroll
      for (int mi = 0; mi < 4; ++mi)
#pragma unroll
        for (int ni = 0; ni < 4; ++ni)
          acc[mi][ni] = __builtin_amdgcn_mfma_f32_16x16x32_bf16(
              af[mi], bfr[ni], acc[mi][ni], 0, 0, 0);
    }
    __syncthreads();
  }

  // epilogue; C/D layout: col = lane&15, row = (lane>>4)*4 + reg.
  // 128-col tile maps to exactly one of {Q,K,V} (block-uniform branch).
  const int cmat = nb >> 3;                 // 0:Q 1:K 2:V
  const float* bias = (cmat == 0) ? b0 : (cmat == 1) ? b1 : b2;
#pragma unroll
  for (int mi = 0; mi < 4; ++mi) {
#pragma unroll
    for (int ni = 0; ni < 4; ++ni) {
      const int col = n0 + wn + ni * 16 + l15;
      const int lcol = col & 1023;
      const float bv = bias[lcol];
      if (cmat == 2) {
        // V transposed: Vt[b][d][t]; lane holds 4 consecutive t -> 8B store
        int rowg = m0 + wm + mi * 16 + q4 * 4;
        int bb = rowg >> 11, tt = rowg & 2047;
        bf16x4 pk;
#pragma unroll
        for (int r = 0; r < 4; ++r) pk[r] = (bf16_t)(acc[mi][ni][r] + bv);
        *(bf16x4*)(O2 + (size_t)(bb * 1024 + lcol) * 2048 + tt) = pk;
      } else {
        bf16_t* Om = cmat ? O1 : O0;
#pragma unroll
        for (int r = 0; r < 4; ++r) {
          int row = m0 + wm + mi * 16 + q4 * 4 + r;
          Om[(size_t)row * 1024 + lcol] = (bf16_t)(acc[mi][ni][r] + bv);
        }
      }
    }
  }
}

// ---------------- out NT GEMM: 128x128 tile, dbuf, 2 blocks/CU (f32 out) ----------------
__global__ __launch_bounds__(512, 2)
void gemm_out(const bf16_t* __restrict__ A, const bf16_t* __restrict__ Wm,
              const float* __restrict__ bias, float* __restrict__ OF)
{
  __shared__ __align__(16) bf16_t As[2][128 * BK];   // 32 KB
  __shared__ __align__(16) bf16_t Bs[2][128 * BK];   // 32 KB
  const int t = threadIdx.x, w = t >> 6, lane = t & 63;
  const int l15 = lane & 15, q4 = lane >> 4;
  const int orig = blockIdx.x;
  const int wgid = (orig & 7) * 32 + (orig >> 3);    // XCD-bijective swizzle
  const int mb = wgid >> 3, nbk = wgid & 7;          // 32 m x 8 n
  const int m0 = mb * 128, n0 = nbk * 128;
  const int wm = (w >> 2) * 64, wn = (w & 3) * 32;   // 2x4 wave grid over 128x128

  floatx4 acc[4][2];
#pragma unroll
  for (int mi = 0; mi < 4; ++mi)
#pragma unroll
    for (int ni = 0; ni < 2; ++ni) acc[mi][ni] = (floatx4){0.f, 0.f, 0.f, 0.f};

  auto stage = [&](int buf, int k0) {
#pragma unroll
    for (int c = 0; c < 2; ++c) {
      int chunk = t + c * 512;                 // 0..1023
      int row = chunk >> 3;
      int g = (chunk & 7) ^ (row & 7);
      async16(A  + (size_t)(m0 + row) * 1024 + k0 + g * 8, &As[buf][chunk * 8]);
      async16(Wm + (size_t)(n0 + row) * 1024 + k0 + g * 8, &Bs[buf][chunk * 8]);
    }
  };

  stage(0, 0);
  __syncthreads();
  for (int it = 0; it < 16; ++it) {
    const int cur = it & 1;
    if (it + 1 < 16) stage(cur ^ 1, (it + 1) * BK);

#pragma unroll
    for (int kk = 0; kk < 2; ++kk) {
      bf16x8 af[4], bfr[2];
#pragma unroll
      for (int i = 0; i < 4; ++i) {
        int ra = wm + i * 16 + l15;
        int pa = (kk * 4 + q4) ^ (ra & 7);
        af[i] = *(const bf16x8*)&As[cur][ra * BK + pa * 8];
      }
#pragma unroll
      for (int i = 0; i < 2; ++i) {
        int rb = wn + i * 16 + l15;
        int pb = (kk * 4 + q4) ^ (rb & 7);
        bfr[i] = *(const bf16x8*)&Bs[cur][rb * BK + pb * 8];
      }
#pragma unroll
      for (int mi = 0; mi < 4; ++mi)
#pragma unroll
        for (int ni = 0; ni < 2; ++ni)
          acc[mi][ni] = __builtin_amdgcn_mfma_f32_16x16x32_bf16(
              af[mi], bfr[ni], acc[mi][ni], 0, 0, 0);
    }
    __syncthreads();
  }

#pragma unroll
  for (int mi = 0; mi < 4; ++mi)
#pragma unroll
    for (int ni = 0; ni < 2; ++ni) {
      const int col = n0 + wn + ni * 16 + l15;
      const float bv = bias[col];
#pragma unroll
      for (int r = 0; r < 4; ++r) {
        int row = m0 + wm + mi * 16 + q4 * 4 + r;
        OF[(size_t)row * 1024 + col] = acc[mi][ni][r] + bv;
      }
    }
}

// ---------------- windowed flash attention: j-tiles {qb-1, qb} only ----------------
// decay e^{-(i-j)} makes keys at distance >64 weigh < e^{-58}: below f32 ulp.
__global__ __launch_bounds__(256, 3)
void attn_kernel(const bf16_t* __restrict__ Qb, const bf16_t* __restrict__ Kb,
                 const bf16_t* __restrict__ Vt, bf16_t* __restrict__ AO)
{
  __shared__ __align__(16) bf16_t Ks[2][64 * 64];
  __shared__ __align__(16) bf16_t Vs[2][64 * 64];
  __shared__ __align__(16) bf16_t Ps[4][16][72];

  const int t = threadIdx.x, w = t >> 6, lane = t & 63;
  const int l15 = lane & 15, q4 = lane >> 4;
  const int bh = blockIdx.x & 31, qb = blockIdx.x >> 5;
  const int b = bh >> 4, h = bh & 15;
  const int i0 = qb * 64;
  const int jstart = (qb > 0) ? (qb - 1) : 0;
  const int nIter = qb - jstart + 1;      // 1 (qb==0) or 2

  const float C1 = 0.125f * LOG2E;        // (1/sqrt(64)) * log2e
  const float CL = LOG2E;
  const float Er[4] = {1.0f, 2.71828182846f, 7.38905609893f, 20.0855369232f};

  const bf16_t* qp = Qb + ((size_t)(b * 2048 + i0 + w * 16 + l15)) * 1024 + h * 64 + q4 * 8;
  const bf16x8 qf0 = *(const bf16x8*)qp;
  const bf16x8 qf1 = *(const bf16x8*)(qp + 32);

  floatx4 o_acc[4], lsum;
  lsum = (floatx4){0.f, 0.f, 0.f, 0.f};
#pragma unroll
  for (int dt = 0; dt < 4; ++dt) o_acc[dt] = (floatx4){0.f, 0.f, 0.f, 0.f};
  bf16x8 ones;
#pragma unroll
  for (int e = 0; e < 8; ++e) ones[e] = (bf16_t)1.0f;

  float dm[4];
#pragma unroll
  for (int mt = 0; mt < 4; ++mt)
    dm[mt] = (float)(jstart * 64 + mt * 16 + q4 * 4 - w * 16 - l15 - i0) * CL;
  const int relMask = w * 16 + l15;

  const int chA = w * 128 + lane, chB = chA + 64;
  const int rA = chA >> 3, rB = chB >> 3;
  const int sA = (chA & 7) ^ (rA & 7), sB = (chB & 7) ^ (rB & 7);
  const bf16_t* kpA = Kb + ((size_t)(b * 2048 + jstart * 64 + rA)) * 1024 + h * 64 + sA * 8;
  const bf16_t* kpB = Kb + ((size_t)(b * 2048 + jstart * 64 + rB)) * 1024 + h * 64 + sB * 8;
  const bf16_t* vpA = Vt + ((size_t)(b * 1024 + h * 64 + rA)) * 2048 + jstart * 64 + sA * 8;
  const bf16_t* vpB = Vt + ((size_t)(b * 1024 + h * 64 + rB)) * 2048 + jstart * 64 + sB * 8;

  auto stage = [&](int buf) {
    async16(kpA, &Ks[buf][chA * 8]);
    async16(kpB, &Ks[buf][chB * 8]);
    async16(vpA, &Vs[buf][chA * 8]);
    async16(vpB, &Vs[buf][chB * 8]);
    kpA += 65536; kpB += 65536;
    vpA += 64;    vpB += 64;
  };

  stage(0);
  for (int it = 0; it < nIter; ++it) {
    __syncthreads();
    if (it + 1 < nIter) stage(1);
    const int cur = it;

    const bool diag = (it == nIter - 1);
#pragma unroll
    for (int mt = 0; mt < 4; ++mt) {
      int row = mt * 16 + l15;
      int s0 = q4 ^ (row & 7);
      int s1 = (4 + q4) ^ (row & 7);
      bf16x8 kf0 = *(const bf16x8*)&Ks[cur][row * 64 + s0 * 8];
      bf16x8 kf1 = *(const bf16x8*)&Ks[cur][row * 64 + s1 * 8];
      floatx4 s4 = __builtin_amdgcn_mfma_f32_16x16x32_bf16(kf0, qf0,
                       (floatx4){0.f, 0.f, 0.f, 0.f}, 0, 0, 0);
      s4 = __builtin_amdgcn_mfma_f32_16x16x32_bf16(kf1, qf1, s4, 0, 0, 0);

      float p[4];
#pragma unroll
      for (int r = 0; r < 4; ++r) {
        float v = EXP2(fmaf(s4[r], C1, dm[mt])) * Er[r];
        if (diag && (mt * 16 + q4 * 4 + r) > relMask) v = 0.f;
        p[r] = v;
      }
      uint2 pk2;
      pk2.x = pack_bf16_trunc(p[0], p[1]);
      pk2.y = pack_bf16_trunc(p[2], p[3]);
      *(uint2*)&Ps[w][l15][mt * 16 + q4 * 4] = pk2;
      dm[mt] += 64.0f * CL;
    }

    __builtin_amdgcn_s_waitcnt(0xC07F);  // lgkmcnt(0): own-wave P writes visible

    bf16x8 pf0 = *(const bf16x8*)&Ps[w][l15][q4 * 8];
    bf16x8 pf1 = *(const bf16x8*)&Ps[w][l15][32 + q4 * 8];
    lsum = __builtin_amdgcn_mfma_f32_16x16x32_bf16(pf0, ones, lsum, 0, 0, 0);
    lsum = __builtin_amdgcn_mfma_f32_16x16x32_bf16(pf1, ones, lsum, 0, 0, 0);
#pragma unroll
    for (int dt = 0; dt < 4; ++dt) {
      int row = dt * 16 + l15;
      int s0 = q4 ^ (row & 7);
      int s1 = (4 + q4) ^ (row & 7);
      bf16x8 vf0 = *(const bf16x8*)&Vs[cur][row * 64 + s0 * 8];
      bf16x8 vf1 = *(const bf16x8*)&Vs[cur][row * 64 + s1 * 8];
      o_acc[dt] = __builtin_amdgcn_mfma_f32_16x16x32_bf16(pf0, vf0, o_acc[dt], 0, 0, 0);
      o_acc[dt] = __builtin_amdgcn_mfma_f32_16x16x32_bf16(pf1, vf1, o_acc[dt], 0, 0, 0);
    }
  }

  floatx4 inv;
#pragma unroll
  for (int r = 0; r < 4; ++r) inv[r] = 1.0f / lsum[r];
#pragma unroll
  for (int dt = 0; dt < 4; ++dt)
#pragma unroll
    for (int r = 0; r < 4; ++r) {
      int i = i0 + w * 16 + q4 * 4 + r;
      AO[((size_t)(b * 2048 + i)) * 1024 + h * 64 + dt * 16 + l15] =
          (bf16_t)(o_acc[dt][r] * inv[r]);
    }
}

// ---------------- launch ----------------
extern "C" void kernel_launch(void* const* d_in, const int* in_sizes, int n_in,
                              void* d_out, int out_size, void* d_ws, size_t ws_size,
                              hipStream_t stream) {
  const float* x  = (const float*)d_in[0];
  const float* Wq = (const float*)d_in[1];
  const float* bq = (const float*)d_in[2];
  const float* Wk = (const float*)d_in[3];
  const float* bk = (const float*)d_in[4];
  const float* Wv = (const float*)d_in[5];
  const float* bv = (const float*)d_in[6];
  const float* Wo = (const float*)d_in[7];
  const float* bo = (const float*)d_in[8];

  char* ws = (char*)d_ws;                      // needs >= 48 MB
  bf16_t* xb  = (bf16_t*)(ws);                 //  8 MB
  bf16_t* wqb = (bf16_t*)(ws + (8u  << 20));   //  2 MB (wq,wk,wv,wo contiguous)
  bf16_t* wob = (bf16_t*)(ws + (14u << 20));
  bf16_t* Qb  = (bf16_t*)(ws + (16u << 20));   //  8 MB  [b,t,h,d]
  bf16_t* Kb  = (bf16_t*)(ws + (24u << 20));   //  8 MB  [b,t,h,d]
  bf16_t* Vtb = (bf16_t*)(ws + (32u << 20));   //  8 MB  [b,h*d,t]
  bf16_t* AOb = (bf16_t*)(ws + (40u << 20));   //  8 MB  [b,t,h,d]

  castall<<<8192, 256, 0, stream>>>(x, Wq, Wk, Wv, Wo, xb, wqb);

  // QKV over stacked W [3072x1024]: 768 blocks (32m x 24n), 4 blocks/CU,
  // all co-resident in one round.
  gemm_qkv<<<768, 256, 0, stream>>>(
      xb, wqb, bq, bk, bv, Qb, Kb, Vtb);

  attn_kernel<<<1024, 256, 0, stream>>>(Qb, Kb, Vtb, AOb);

  // out: 256 blocks (32 m x 8 n) x 512 threads, dbuf, 2 blocks/CU
  gemm_out<<<256, 512, 0, stream>>>(AOb, wob, bo, (float*)d_out);
}